// Round 7
// baseline (66.620 us; speedup 1.0000x reference)
//
#include <hip/hip_runtime.h>
#include <hip/hip_bf16.h>
#include <stdint.h>

#define N_W 96
#define N_F 96
#define NAG 192                      // total agents
#define NP1 97
#define W_ELEMS (N_W * NP1 * NP1)    // 903264 (divisible by 4)
#define R_ELEMS (NAG * NAG)          // 36864
#define WB ((W_ELEMS / 4 + 255) / 256)   // 883
#define RB ((R_ELEMS / 4 + 255) / 256)   // 36

// Decode one-hot tensors into packed index form.
// packed word [a*64 + s] = pref[a][s] | (pref[a][s+64] << 16)  (high half valid for s<33)
// ord[r] = dictating agent in round r (0..95 worker, 96..191 firm).
__global__ __launch_bounds__(256) void decode_kernel(
    const float* __restrict__ W, const float* __restrict__ F,
    const float* __restrict__ R,
    short* __restrict__ ps, short* __restrict__ ord) {
    int b = blockIdx.x;
    if (b < 2 * WB) {
        const float* src = (b < WB) ? W : F;
        int abase = (b < WB) ? 0 : N_W;
        int i4 = (b - ((b < WB) ? 0 : WB)) * 256 + threadIdx.x;
        if (i4 < W_ELEMS / 4) {
            float4 v = ((const float4*)src)[i4];
            int base = i4 * 4;
            #pragma unroll
            for (int u = 0; u < 4; ++u) {
                float x = (u == 0) ? v.x : (u == 1) ? v.y : (u == 2) ? v.z : v.w;
                if (x > 0.5f) {
                    int idx = base + u;
                    int a = idx / (NP1 * NP1);
                    int rem = idx - a * (NP1 * NP1);
                    int j = rem / NP1;          // option (firm/worker or 96=unmatch)
                    int k = rem - j * NP1;      // rank
                    int slot = (k < 64) ? (2 * k) : (2 * (k - 64) + 1);
                    ps[(abase + a) * 128 + slot] = (short)j;
                }
            }
        }
    } else {
        int i4 = (b - 2 * WB) * 256 + threadIdx.x;
        if (i4 < R_ELEMS / 4) {
            float4 v = ((const float4*)R)[i4];
            int base = i4 * 4;
            #pragma unroll
            for (int u = 0; u < 4; ++u) {
                float x = (u == 0) ? v.x : (u == 1) ? v.y : (u == 2) ? v.z : v.w;
                if (x > 0.5f) {
                    int idx = base + u;
                    int a = idx / NAG;
                    int r = idx - a * NAG;
                    ord[r] = (short)a;
                }
            }
        }
    }
}

#define LOAD8(dst, rb) \
    dst##0 = s_pko[((rb) << 6) + t];        \
    dst##1 = s_pko[((rb) << 6) + 64 + t];   \
    dst##2 = s_pko[((rb) << 6) + 128 + t];  \
    dst##3 = s_pko[((rb) << 6) + 192 + t];  \
    dst##4 = s_pko[((rb) << 6) + 256 + t];  \
    dst##5 = s_pko[((rb) << 6) + 320 + t];  \
    dst##6 = s_pko[((rb) << 6) + 384 + t];  \
    dst##7 = s_pko[((rb) << 6) + 448 + t];

#define GROUP8(rb, P_, ov_) do {                        \
    ROUND((rb) + 0, P_##0, (int)((ov_).x & 0xFFFFu));   \
    ROUND((rb) + 1, P_##1, (int)((ov_).x >> 16));       \
    ROUND((rb) + 2, P_##2, (int)((ov_).y & 0xFFFFu));   \
    ROUND((rb) + 3, P_##3, (int)((ov_).y >> 16));       \
    ROUND((rb) + 4, P_##4, (int)((ov_).z & 0xFFFFu));   \
    ROUND((rb) + 5, P_##5, (int)((ov_).z >> 16));       \
    ROUND((rb) + 6, P_##6, (int)((ov_).w & 0xFFFFu));   \
    ROUND((rb) + 7, P_##7, (int)((ov_).w >> 16));       \
} while (0)

__global__ __launch_bounds__(256, 1) void sd_kernel(
    const uint32_t* __restrict__ pk_g, const short* __restrict__ ord_g,
    float* __restrict__ out) {
    __shared__ __align__(16) uint32_t s_pko[NAG * 64];   // 48 KiB, round-ordered prefs
    __shared__ uint32_t s_match[NAG];

    const int t = threadIdx.x;
    const unsigned short* og = (const unsigned short*)ord_g;

    // staging: s_pko[r][lane] = pk[ord[r]][lane]  (indirection paid here, in parallel)
    for (int idx = t; idx < NAG * 16; idx += 256) {
        int r = idx >> 4, q = idx & 15;
        int a = (int)og[r];
        ((uint4*)s_pko)[idx] = ((const uint4*)(pk_g + (a << 6)))[q];
    }
    __syncthreads();

    if (t < 64) {
        uint64_t rWlo = 0, rWhi = 0, rFlo = 0, rFhi = 0;   // removal masks (uniform -> SGPR)
        uint32_t cell0 = 0xFFFFFFFFu, cell1 = 0xFFFFFFFFu, cell2 = 0xFFFFFFFFu;

        auto ROUND = [&](int r, uint32_t P, int a) {
            // per-lane derive (independent of masks -> off-chain)
            uint32_t j1 = P & 0xFFFFu, j2 = P >> 16;
            uint32_t s1 = j1 & 63u, s2 = j2 & 63u;
            uint32_t lo1 = (j1 < 64u) ? 1u : 0u;
            uint32_t hi1 = (j1 >= 64u && j1 < 96u) ? 1u : 0u;
            uint32_t lo2 = (j2 < 64u) ? 1u : 0u;
            uint32_t hi2 = (j2 >= 64u && j2 < 96u) ? 1u : 0u;
            // uniform scalar, branchless
            int isW = (a < 96) ? 1 : 0;
            int aa  = isW ? a : (a - 96);
            int sh  = aa & 63;
            int ahi = aa >> 6;                        // 0 for 0..63, 1 for 64..95
            uint64_t sb = 1ull << sh;
            uint64_t ownlo = isW ? rWlo : rFlo;
            uint64_t ownhi = isW ? rWhi : rFhi;
            uint64_t ownw  = ahi ? ownhi : ownlo;
            uint32_t alive = 1u - ((uint32_t)(ownw >> sh) & 1u);
            uint64_t slo = ahi ? 0ull : sb;
            uint64_t shi = ahi ? sb : 0ull;
            rWlo |= isW ? slo : 0ull;  rWhi |= isW ? shi : 0ull;   // self-removal
            rFlo |= isW ? 0ull : slo;  rFhi |= isW ? 0ull : shi;
            uint64_t olo = isW ? rFlo : rWlo;
            uint64_t ohi = isW ? rFhi : rWhi;
            // per-lane availability test (on-chain VALU)
            uint32_t bad1 = (((uint32_t)(olo >> s1)) & lo1) | (((uint32_t)(ohi >> s1)) & hi1);
            uint32_t bad2 = (((uint32_t)(olo >> s2)) & lo2) | (((uint32_t)(ohi >> s2)) & hi2);
            unsigned long long m1 = __ballot(bad1 == 0u);
            unsigned long long m2 = __ballot(bad2 == 0u) & 0x1FFFFFFFFull;
            int k = (m1 != 0ull) ? (__ffsll(m1) - 1) : (63 + __ffsll(m2));
            uint32_t pc = (uint32_t)__builtin_amdgcn_readlane((int)P, k & 63);
            uint32_t js = (k >= 64) ? (pc >> 16) : (pc & 0xFFFFu);
            // chosen removal + cell (scalar, branchless)
            uint32_t take = alive & ((js < 96u) ? 1u : 0u);
            uint64_t cb = 1ull << (js & 63u);
            int jhi = (int)(js >> 6);
            uint64_t clo = (take && !jhi) ? cb : 0ull;
            uint64_t chi = (take &&  jhi) ? cb : 0ull;
            rFlo |= isW ? clo : 0ull;  rFhi |= isW ? chi : 0ull;
            rWlo |= isW ? 0ull : clo;  rWhi |= isW ? 0ull : chi;
            uint32_t cellu = alive ? (isW ? (uint32_t)(aa * NP1 + (int)js)
                                          : (uint32_t)((int)js * NP1 + aa))
                                   : 0xFFFFFFFFu;
            // per-lane accumulation (off-chain): lane r%64 keeps round r's cell
            cell0 = (t == r)       ? cellu : cell0;
            cell1 = (t == r - 64)  ? cellu : cell1;
            cell2 = (t == r - 128) ? cellu : cell2;
        };

        uint32_t Pa0, Pa1, Pa2, Pa3, Pa4, Pa5, Pa6, Pa7;
        uint32_t Pb0, Pb1, Pb2, Pb3, Pb4, Pb5, Pb6, Pb7;
        uint4 ovA = ((const uint4*)og)[0];     // uniform -> s_load
        uint4 ovB;
        LOAD8(Pa, 0);
        for (int g = 0; g < 24; g += 2) {
            ovB = ((const uint4*)og)[g + 1];               // prefetch next group's ids
            LOAD8(Pb, (g + 1) << 3);                       // prefetch next group's prefs
            GROUP8(g << 3, Pa, ovA);
            int g2 = (g + 2 < 24) ? (g + 2) : 23;          // clamp: harmless reload at end
            ovA = ((const uint4*)og)[g2];
            LOAD8(Pa, g2 << 3);
            GROUP8((g + 1) << 3, Pb, ovB);
        }
        s_match[t] = cell0; s_match[64 + t] = cell1; s_match[128 + t] = cell2;
    } else {
        // waves 1-3: zero-fill output concurrently with wave 0's loop
        for (int i = t - 64; i < 2352; i += 192)
            ((float4*)out)[i] = make_float4(0.f, 0.f, 0.f, 0.f);
        if (t == 64) out[9408] = 0.f;
    }
    __syncthreads();
    if (t < NAG) {
        uint32_t c = s_match[t];
        if (c != 0xFFFFFFFFu) out[c] = 1.0f;
    }
}

extern "C" void kernel_launch(void* const* d_in, const int* in_sizes, int n_in,
                              void* d_out, int out_size, void* d_ws, size_t ws_size,
                              hipStream_t stream) {
    const float* W = (const float*)d_in[0];
    const float* F = (const float*)d_in[1];
    const float* R = (const float*)d_in[2];
    float* out = (float*)d_out;

    uint32_t* packed = (uint32_t*)d_ws;                 // NAG*64 u32 = 48 KiB
    short* ord = (short*)((char*)d_ws + NAG * 64 * 4);  // 192 shorts

    decode_kernel<<<2 * WB + RB, 256, 0, stream>>>(W, F, R, (short*)packed, ord);
    sd_kernel<<<1, 256, 0, stream>>>(packed, ord, out);
}

// Round 8
// 49.222 us; speedup vs baseline: 1.3535x; 1.3535x over previous
//
#include <hip/hip_runtime.h>
#include <hip/hip_bf16.h>
#include <stdint.h>

#define N_W 96
#define NAG 192                      // total agents
#define NP1 97
#define W_ELEMS (N_W * NP1 * NP1)    // 903264 (divisible by 4)
#define R_ELEMS (NAG * NAG)          // 36864
#define WB ((W_ELEMS / 4 + 255) / 256)   // 883
#define RB ((R_ELEMS / 4 + 255) / 256)   // 36

// Decode one-hot tensors into packed index form.
// packed word [a*64 + s] = pref[a][s] | (pref[a][s+64] << 16)  (high half valid for s<33)
// ord[r] = dictating agent in round r (0..95 worker, 96..191 firm).
__global__ __launch_bounds__(256) void decode_kernel(
    const float* __restrict__ W, const float* __restrict__ F,
    const float* __restrict__ R,
    short* __restrict__ ps, short* __restrict__ ord) {
    int b = blockIdx.x;
    if (b < 2 * WB) {
        const float* src = (b < WB) ? W : F;
        int abase = (b < WB) ? 0 : N_W;
        int i4 = (b - ((b < WB) ? 0 : WB)) * 256 + threadIdx.x;
        if (i4 < W_ELEMS / 4) {
            float4 v = ((const float4*)src)[i4];
            int base = i4 * 4;
            #pragma unroll
            for (int u = 0; u < 4; ++u) {
                float x = (u == 0) ? v.x : (u == 1) ? v.y : (u == 2) ? v.z : v.w;
                if (x > 0.5f) {
                    int idx = base + u;
                    int a = idx / (NP1 * NP1);
                    int rem = idx - a * (NP1 * NP1);
                    int j = rem / NP1;          // option (firm/worker or 96=unmatch)
                    int k = rem - j * NP1;      // rank
                    int slot = (k < 64) ? (2 * k) : (2 * (k - 64) + 1);
                    ps[(abase + a) * 128 + slot] = (short)j;
                }
            }
        }
    } else {
        int i4 = (b - 2 * WB) * 256 + threadIdx.x;
        if (i4 < R_ELEMS / 4) {
            float4 v = ((const float4*)R)[i4];
            int base = i4 * 4;
            #pragma unroll
            for (int u = 0; u < 4; ++u) {
                float x = (u == 0) ? v.x : (u == 1) ? v.y : (u == 2) ? v.z : v.w;
                if (x > 0.5f) {
                    int idx = base + u;
                    int a = idx / NAG;
                    int r = idx - a * NAG;
                    ord[r] = (short)a;
                }
            }
        }
    }
}

#define LOAD8(dst, rb) \
    dst##0 = s_pko[((rb) << 6) + t];        \
    dst##1 = s_pko[((rb) << 6) + 64 + t];   \
    dst##2 = s_pko[((rb) << 6) + 128 + t];  \
    dst##3 = s_pko[((rb) << 6) + 192 + t];  \
    dst##4 = s_pko[((rb) << 6) + 256 + t];  \
    dst##5 = s_pko[((rb) << 6) + 320 + t];  \
    dst##6 = s_pko[((rb) << 6) + 384 + t];  \
    dst##7 = s_pko[((rb) << 6) + 448 + t];

// dictator ids for a group of 8 (uniform SALU extracts)
#define AEXT(ov_) \
    const int A0 = (int)((ov_).x & 0xFFFFu), A1 = (int)((ov_).x >> 16), \
              A2 = (int)((ov_).y & 0xFFFFu), A3 = (int)((ov_).y >> 16), \
              A4 = (int)((ov_).z & 0xFFFFu), A5 = (int)((ov_).z >> 16), \
              A6 = (int)((ov_).w & 0xFFFFu), A7 = (int)((ov_).w >> 16);

// Phase A: speculative query for round q from group-start (live) masks.
// Independent across q -> fully pipelined. Fast path covers ranks 0..63 (m1).
#define QP(q, P_) \
    const uint64_t qlo_##q = (A##q < 96) ? rFlo : rWlo; \
    const uint64_t qhi_##q = (A##q < 96) ? rFhi : rWhi; \
    const uint32_t jj_##q = (P_##q) & 0xFFFFu; \
    const uint32_t av_##q = (uint32_t)((((jj_##q >= 64u) ? qhi_##q : qlo_##q) >> (jj_##q & 63u))) & 1u; \
    const unsigned long long m_##q = __ballot(av_##q == 0u); \
    const bool z_##q = (m_##q == 0ull); \
    const int k_##q = __ffsll(m_##q) - 1; \
    const uint32_t js_##q = ((uint32_t)__builtin_amdgcn_readlane((int)(P_##q), k_##q & 63)) & 0xFFFFu;

// Phase B: serial scalar resolve; requery only on collision / stale-empty-m1.
#define RES(q, r, P_) do { \
    const int a_ = A##q; \
    if (a_ < 96) { \
        const int sh_ = a_ & 63; \
        const uint64_t own_ = (a_ >= 64) ? rWhi : rWlo; \
        if (((own_ >> sh_) & 1ull) == 0ull) { \
            uint32_t js_ = js_##q; \
            bool redo_ = z_##q; \
            if (!redo_ && js_ < 96u) \
                redo_ = ((((js_ >= 64u) ? rFhi : rFlo) >> (js_ & 63u)) & 1ull) != 0ull; \
            if (redo_) js_ = FULLQ(P_##q, rFlo, rFhi); \
            s_match[r] = (uint32_t)(a_ * NP1 + (int)js_); \
            if (js_ < 96u) { \
                if (js_ >= 64u) rFhi |= 1ull << (js_ & 63u); else rFlo |= 1ull << js_; } \
            if (a_ >= 64) rWhi |= 1ull << sh_; else rWlo |= 1ull << sh_; \
        } \
    } else { \
        const int aa_ = a_ - 96; \
        const int sh_ = aa_ & 63; \
        const uint64_t own_ = (aa_ >= 64) ? rFhi : rFlo; \
        if (((own_ >> sh_) & 1ull) == 0ull) { \
            uint32_t js_ = js_##q; \
            bool redo_ = z_##q; \
            if (!redo_ && js_ < 96u) \
                redo_ = ((((js_ >= 64u) ? rWhi : rWlo) >> (js_ & 63u)) & 1ull) != 0ull; \
            if (redo_) js_ = FULLQ(P_##q, rWlo, rWhi); \
            s_match[r] = (uint32_t)((int)js_ * NP1 + aa_); \
            if (js_ < 96u) { \
                if (js_ >= 64u) rWhi |= 1ull << (js_ & 63u); else rWlo |= 1ull << js_; } \
            if (aa_ >= 64) rFhi |= 1ull << sh_; else rFlo |= 1ull << sh_; \
        } \
    } \
} while (0)

#define GROUP8(rb, P_, ov_) do { \
    AEXT(ov_) \
    QP(0, P_) QP(1, P_) QP(2, P_) QP(3, P_) \
    QP(4, P_) QP(5, P_) QP(6, P_) QP(7, P_) \
    RES(0, (rb) + 0, P_); RES(1, (rb) + 1, P_); \
    RES(2, (rb) + 2, P_); RES(3, (rb) + 3, P_); \
    RES(4, (rb) + 4, P_); RES(5, (rb) + 5, P_); \
    RES(6, (rb) + 6, P_); RES(7, (rb) + 7, P_); \
} while (0)

__global__ __launch_bounds__(256, 1) void sd_kernel(
    const uint32_t* __restrict__ pk_g, const short* __restrict__ ord_g,
    float* __restrict__ out) {
    __shared__ __align__(16) uint32_t s_pko[NAG * 64];   // 48 KiB, round-ordered prefs
    __shared__ uint32_t s_match[NAG];

    const int t = threadIdx.x;
    const unsigned short* og = (const unsigned short*)ord_g;

    // staging: s_pko[r][lane] = pk[ord[r]][lane]  (indirection paid here, in parallel)
    for (int idx = t; idx < NAG * 16; idx += 256) {
        int r = idx >> 4, q = idx & 15;
        int a = (int)og[r];
        ((uint4*)s_pko)[idx] = ((const uint4*)(pk_g + (a << 6)))[q];
    }
    if (t < NAG) s_match[t] = 0xFFFFFFFFu;   // dead rounds must read as "no match"
    __syncthreads();

    if (t < 64) {
        uint64_t rWlo = 0, rWhi = 0, rFlo = 0, rFhi = 0;   // removal masks (uniform -> SGPR)

        // full two-tier query from live masks (requery / rank>=64 fallback; rare)
        auto FULLQ = [&](uint32_t P, uint64_t olo, uint64_t ohi) -> uint32_t {
            uint32_t j1 = P & 0xFFFFu;
            uint32_t a1 = (uint32_t)((((j1 >= 64u) ? ohi : olo) >> (j1 & 63u))) & 1u;
            unsigned long long m1 = __ballot(a1 == 0u);
            uint32_t j2 = P >> 16;
            uint32_t a2 = (uint32_t)((((j2 >= 64u) ? ohi : olo) >> (j2 & 63u))) & 1u;
            unsigned long long m2 = __ballot(a2 == 0u) & 0x1FFFFFFFFull;  // lanes 33+ garbage
            int k = (m1 != 0ull) ? (__ffsll(m1) - 1) : (63 + __ffsll(m2));
            uint32_t pc = (uint32_t)__builtin_amdgcn_readlane((int)P, k & 63);
            return (k >= 64) ? (pc >> 16) : (pc & 0xFFFFu);
        };

        uint32_t Pa0, Pa1, Pa2, Pa3, Pa4, Pa5, Pa6, Pa7;
        uint32_t Pb0, Pb1, Pb2, Pb3, Pb4, Pb5, Pb6, Pb7;
        uint4 ovA = ((const uint4*)og)[0];     // uniform -> s_load
        uint4 ovB;
        LOAD8(Pa, 0);
        for (int g = 0; g < 24; g += 2) {
            ovB = ((const uint4*)og)[g + 1];               // prefetch next group's ids
            LOAD8(Pb, (g + 1) << 3);                       // prefetch next group's prefs
            GROUP8(g << 3, Pa, ovA);
            int g2 = (g + 2 < 24) ? (g + 2) : 23;          // clamp: harmless reload at end
            ovA = ((const uint4*)og)[g2];
            LOAD8(Pa, g2 << 3);
            GROUP8((g + 1) << 3, Pb, ovB);
        }
    } else {
        // waves 1-3: zero-fill output concurrently with wave 0's loop
        for (int i = t - 64; i < 2352; i += 192)
            ((float4*)out)[i] = make_float4(0.f, 0.f, 0.f, 0.f);
        if (t == 64) out[9408] = 0.f;
    }
    __syncthreads();
    if (t < NAG) {
        uint32_t c = s_match[t];
        if (c != 0xFFFFFFFFu) out[c] = 1.0f;
    }
}

extern "C" void kernel_launch(void* const* d_in, const int* in_sizes, int n_in,
                              void* d_out, int out_size, void* d_ws, size_t ws_size,
                              hipStream_t stream) {
    const float* W = (const float*)d_in[0];
    const float* F = (const float*)d_in[1];
    const float* R = (const float*)d_in[2];
    float* out = (float*)d_out;

    uint32_t* packed = (uint32_t*)d_ws;                 // NAG*64 u32 = 48 KiB
    short* ord = (short*)((char*)d_ws + NAG * 64 * 4);  // 192 shorts

    decode_kernel<<<2 * WB + RB, 256, 0, stream>>>(W, F, R, (short*)packed, ord);
    sd_kernel<<<1, 256, 0, stream>>>(packed, ord, out);
}

// Round 10
// 46.118 us; speedup vs baseline: 1.4446x; 1.0673x over previous
//
#include <hip/hip_runtime.h>
#include <hip/hip_bf16.h>
#include <stdint.h>

#define N_W 96
#define NAG 192                      // total agents
#define NP1 97
#define W_ELEMS (N_W * NP1 * NP1)    // 903264 (divisible by 4)
#define R_ELEMS (NAG * NAG)          // 36864
#define WB ((W_ELEMS / 4 + 255) / 256)   // 883
#define RB ((R_ELEMS / 4 + 255) / 256)   // 36

// Decode one-hot tensors into packed index form.
// packed word [a*64 + s] = pref[a][s] | (pref[a][s+64] << 16)  (high half valid for s<33)
// ord[r] = dictating agent in round r (0..95 worker, 96..191 firm).
__global__ __launch_bounds__(256) void decode_kernel(
    const float* __restrict__ W, const float* __restrict__ F,
    const float* __restrict__ R,
    short* __restrict__ ps, short* __restrict__ ord) {
    int b = blockIdx.x;
    if (b < 2 * WB) {
        const float* src = (b < WB) ? W : F;
        int abase = (b < WB) ? 0 : N_W;
        int i4 = (b - ((b < WB) ? 0 : WB)) * 256 + threadIdx.x;
        if (i4 < W_ELEMS / 4) {
            float4 v = ((const float4*)src)[i4];
            int base = i4 * 4;
            #pragma unroll
            for (int u = 0; u < 4; ++u) {
                float x = (u == 0) ? v.x : (u == 1) ? v.y : (u == 2) ? v.z : v.w;
                if (x > 0.5f) {
                    int idx = base + u;
                    int a = idx / (NP1 * NP1);
                    int rem = idx - a * (NP1 * NP1);
                    int j = rem / NP1;          // option (firm/worker or 96=unmatch)
                    int k = rem - j * NP1;      // rank
                    int slot = (k < 64) ? (2 * k) : (2 * (k - 64) + 1);
                    ps[(abase + a) * 128 + slot] = (short)j;
                }
            }
        }
    } else {
        int i4 = (b - 2 * WB) * 256 + threadIdx.x;
        if (i4 < R_ELEMS / 4) {
            float4 v = ((const float4*)R)[i4];
            int base = i4 * 4;
            #pragma unroll
            for (int u = 0; u < 4; ++u) {
                float x = (u == 0) ? v.x : (u == 1) ? v.y : (u == 2) ? v.z : v.w;
                if (x > 0.5f) {
                    int idx = base + u;
                    int a = idx / NAG;
                    int r = idx - a * NAG;
                    ord[r] = (short)a;
                }
            }
        }
    }
}

// Single-block sequential serial dictatorship.
// ROLLED inner loop (I$-resident body), SGPR masks, readlane for uniform moves,
// cmp+cndmask lane-capture, depth-1 static-address LDS prefetch of prefs.
__global__ __launch_bounds__(256, 1) void sd_kernel(
    const uint32_t* __restrict__ pk_g, const short* __restrict__ ord_g,
    float* __restrict__ out) {
    __shared__ __align__(16) uint32_t s_pko[NAG * 64 + 64];  // +64: prefetch overrun pad
    __shared__ uint32_t s_match[NAG];

    const int t = threadIdx.x;
    const unsigned short* og = (const unsigned short*)ord_g;

    // staging: s_pko[r][lane] = pk[ord[r]][lane]  (indirection paid here, in parallel)
    for (int idx = t; idx < NAG * 16; idx += 256) {
        int r = idx >> 4, q = idx & 15;
        int a = (int)og[r];
        ((uint4*)s_pko)[idx] = ((const uint4*)(pk_g + (a << 6)))[q];
    }
    __syncthreads();

    if (t < 64) {
        uint32_t ov0 = og[t], ov1 = og[64 + t], ov2 = og[128 + t];
        uint64_t rWlo = 0, rWhi = 0, rFlo = 0, rFhi = 0;     // uniform -> SGPR
        uint32_t c0 = 0xFFFFFFFFu, c1 = 0xFFFFFFFFu, c2 = 0xFFFFFFFFu;
        uint32_t Pc = s_pko[t];                               // round 0 prefs

        auto runseg = [&](uint32_t ordv, uint32_t& cellv, int segbase) {
            #pragma clang loop unroll(disable)
            for (int rr = 0; rr < 64; ++rr) {
                const int r = segbase + rr;
                uint32_t Pn = s_pko[((r + 1) << 6) + t];      // depth-1 prefetch
                int a = __builtin_amdgcn_readlane((int)ordv, rr);   // uniform
                uint32_t j1 = Pc & 0xFFFFu, j2 = Pc >> 16;
                uint32_t s1 = j1 & 63u, s2 = j2 & 63u;
                bool h1 = j1 >= 64u, h2 = j2 >= 64u;
                if (a < 96) {                                 // worker dictates
                    uint64_t own = (a >= 64) ? rWhi : rWlo;
                    uint64_t sb = 1ull << (a & 63);
                    if (a >= 64) rWhi |= sb; else rWlo |= sb; // self-removal
                    if (((own >> (a & 63)) & 1ull) == 0ull) { // alive
                        uint32_t b1 = (h1 ? (uint32_t)(rFhi >> s1)
                                          : (uint32_t)(rFlo >> s1)) & 1u;
                        unsigned long long m1 = __ballot(b1 == 0u);
                        uint32_t js;
                        if (m1 != 0ull) {
                            int k = __ffsll(m1) - 1;
                            js = ((uint32_t)__builtin_amdgcn_readlane((int)Pc, k)) & 0xFFFFu;
                        } else {                              // rare: rank>=64
                            uint32_t b2 = (h2 ? (uint32_t)(rFhi >> s2)
                                              : (uint32_t)(rFlo >> s2)) & 1u;
                            unsigned long long m2 = __ballot(b2 == 0u) & 0x1FFFFFFFFull;
                            int k = __ffsll(m2) - 1;
                            js = ((uint32_t)__builtin_amdgcn_readlane((int)Pc, k)) >> 16;
                        }
                        uint64_t cb = 1ull << (js & 63u);
                        rFlo |= (js < 64u) ? cb : 0ull;       // branchless s_cselect+s_or
                        rFhi |= (js >= 64u && js < 96u) ? cb : 0ull;
                        uint32_t cellu = (uint32_t)(a * NP1) + js;  // uniform
                        cellv = (t == rr) ? cellu : cellv;    // lane-capture (off-chain)
                    }
                } else {                                      // firm dictates
                    int aa = a - 96;
                    uint64_t own = (aa >= 64) ? rFhi : rFlo;
                    uint64_t sb = 1ull << (aa & 63);
                    if (aa >= 64) rFhi |= sb; else rFlo |= sb;
                    if (((own >> (aa & 63)) & 1ull) == 0ull) {
                        uint32_t b1 = (h1 ? (uint32_t)(rWhi >> s1)
                                          : (uint32_t)(rWlo >> s1)) & 1u;
                        unsigned long long m1 = __ballot(b1 == 0u);
                        uint32_t js;
                        if (m1 != 0ull) {
                            int k = __ffsll(m1) - 1;
                            js = ((uint32_t)__builtin_amdgcn_readlane((int)Pc, k)) & 0xFFFFu;
                        } else {
                            uint32_t b2 = (h2 ? (uint32_t)(rWhi >> s2)
                                              : (uint32_t)(rWlo >> s2)) & 1u;
                            unsigned long long m2 = __ballot(b2 == 0u) & 0x1FFFFFFFFull;
                            int k = __ffsll(m2) - 1;
                            js = ((uint32_t)__builtin_amdgcn_readlane((int)Pc, k)) >> 16;
                        }
                        uint64_t cb = 1ull << (js & 63u);
                        rWlo |= (js < 64u) ? cb : 0ull;
                        rWhi |= (js >= 64u && js < 96u) ? cb : 0ull;
                        uint32_t cellu = js * (uint32_t)NP1 + (uint32_t)aa;  // uniform
                        cellv = (t == rr) ? cellu : cellv;    // lane-capture (off-chain)
                    }
                }
                Pc = Pn;
            }
        };
        runseg(ov0, c0, 0);
        runseg(ov1, c1, 64);
        runseg(ov2, c2, 128);
        s_match[t] = c0; s_match[64 + t] = c1; s_match[128 + t] = c2;
    } else {
        // waves 1-3: zero-fill output concurrently with wave 0's loop
        for (int i = t - 64; i < 2352; i += 192)
            ((float4*)out)[i] = make_float4(0.f, 0.f, 0.f, 0.f);
        if (t == 64) out[9408] = 0.f;
    }
    __syncthreads();
    if (t < NAG) {
        uint32_t c = s_match[t];
        if (c != 0xFFFFFFFFu) out[c] = 1.0f;
    }
}

extern "C" void kernel_launch(void* const* d_in, const int* in_sizes, int n_in,
                              void* d_out, int out_size, void* d_ws, size_t ws_size,
                              hipStream_t stream) {
    const float* W = (const float*)d_in[0];
    const float* F = (const float*)d_in[1];
    const float* R = (const float*)d_in[2];
    float* out = (float*)d_out;

    uint32_t* packed = (uint32_t*)d_ws;                 // NAG*64 u32 = 48 KiB
    short* ord = (short*)((char*)d_ws + NAG * 64 * 4);  // 192 shorts

    decode_kernel<<<2 * WB + RB, 256, 0, stream>>>(W, F, R, (short*)packed, ord);
    sd_kernel<<<1, 256, 0, stream>>>(packed, ord, out);
}